// Round 5
// baseline (524.816 us; speedup 1.0000x reference)
//
#include <hip/hip_runtime.h>

// Problem dims (fixed by reference)
#define Bdim 16
#define Sdim 128
#define Mdim 128
#define Ddim 256   // emb dim
#define Hdim 256   // hidden dim
#define NPB 2      // nodes per block
#define NT  512    // threads per block (8 waves)

// Round-4 structure: force memory-level parallelism with global_load_lds DMA.
// Rounds 0-3 all plateaued at ~3.16 TB/s fabric-read (5.1 B/cyc/CU) no matter
// the occupancy (43/63/79%) because the compiler kept VGPR-scheduled loads at
// effective depth ~2-4. Here each wave keeps 8 x 1KB DMAs in flight
// (2-row chunks, double-buffered, s_waitcnt vmcnt(4) gating); 16 waves/CU
// -> ~128 KB in flight per CU, an order of magnitude above what 10 B/cyc/CU
// needs. DMA consumes no VGPRs, so no spill/de-pipeline hazard.
// LDS: 8 waves x 8KB staging (reused as phase-2 partial-sum space) + hid.
// 69.7 KB -> 2 blocks/CU. Phase 2/3 unchanged from gcn_fused3.
__global__ __launch_bounds__(NT, 4) void gcn_dma(
    const float* __restrict__ src,
    const float* __restrict__ neigh,
    const float* __restrict__ Wmap,   // [2D, H] row-major
    const float* __restrict__ bmap,   // [H]
    float* __restrict__ out)          // [B*S, H]
{
    const int tid   = threadIdx.x;
    const int wave  = tid >> 6;       // 0..7
    const int lane  = tid & 63;
    const int lnode = wave >> 2;      // 0..1 local node
    const int mph   = wave & 3;       // 32-row chunk index within node

    // Per-wave staging: 2048 floats (8 KB):
    //   [0..512)    src  buf0 (2 rows x 256)   | after streaming: src partial
    //   [512..1024) src  buf1                  |   at [0..256)
    //   [1024..1536) ngh buf0                  | ngh partial at [256..512)
    //   [1536..2048) ngh buf1
    __shared__ __align__(16) float lds[8 * 2048];   // 64 KiB
    __shared__ float hid[NPB][2 * Ddim];            //  4 KiB
    __shared__ int   s_cnt[8];

    float* stg = &lds[wave * 2048];

    const size_t node = (size_t)(blockIdx.x * NPB + lnode);
    const size_t rowbase = node * (Mdim * Ddim) + (size_t)(mph * 32) * Ddim;
    const float* gs = src   + rowbase + lane * 4;   // per-lane global src
    const float* gn = neigh + rowbase + lane * 4;

    // one DMA instr = 64 lanes x 16B = one full 256-col row into LDS
    #define DMA16(gp, lp)                                                     \
        __builtin_amdgcn_global_load_lds(                                     \
            (const __attribute__((address_space(1))) void*)(gp),              \
            (__attribute__((address_space(3))) void*)(lp), 16, 0, 0)

    // issue chunk c (2 rows of src + 2 rows of neigh = 4 DMAs)
    #define ISSUE(c)                                                          \
        do {                                                                  \
            const int _b = ((c) & 1) * 512;                                   \
            DMA16(gs + ((c) * 2 + 0) * Ddim, stg + _b);                       \
            DMA16(gs + ((c) * 2 + 1) * Ddim, stg + _b + 256);                 \
            DMA16(gn + ((c) * 2 + 0) * Ddim, stg + 1024 + _b);                \
            DMA16(gn + ((c) * 2 + 1) * Ddim, stg + 1024 + _b + 256);          \
        } while (0)

    float4 sacc = make_float4(0.f, 0.f, 0.f, 0.f);
    float4 nacc = make_float4(0.f, 0.f, 0.f, 0.f);
    int cnt = 0;

    ISSUE(0);
    for (int c = 0; c < 16; ++c) {
        if (c < 15) {
            ISSUE(c + 1);                       // 8 DMAs now in flight
            asm volatile("s_waitcnt vmcnt(4)" ::: "memory");  // chunk c landed
        } else {
            asm volatile("s_waitcnt vmcnt(0)" ::: "memory");
        }
        const int b = (c & 1) * 512;
        #pragma unroll
        for (int r = 0; r < 2; ++r) {
            const float4 sv = *(const float4*)&stg[b + r * 256 + lane * 4];
            const float4 nv = *(const float4*)&stg[1024 + b + r * 256 + lane * 4];
            sacc.x += sv.x; sacc.y += sv.y; sacc.z += sv.z; sacc.w += sv.w;
            nacc.x += nv.x; nacc.y += nv.y; nacc.z += nv.z; nacc.w += nv.w;
            int nz = (nv.x != 0.f) | (nv.y != 0.f) | (nv.z != 0.f) | (nv.w != 0.f);
            if (__any(nz)) cnt++;   // wave-wide OR over the row's 256 columns
        }
    }
    #undef ISSUE
    #undef DMA16

    // per-wave partials into own (already-consumed) staging space
    *(float4*)&stg[lane * 4]       = sacc;   // src partial  [0..256)
    *(float4*)&stg[256 + lane * 4] = nacc;   // ngh partial  [256..512)
    if (lane == 0) s_cnt[wave] = cnt;
    __syncthreads();

    // combine 4 waves -> hidden rows. 512 threads = 2 nodes x 512 cols:
    // threads 0..255 build the src-sum half, 256..511 the neigh-mean half.
    {
        const int t    = tid & (Ddim - 1);
        const int half = tid >> 8;
        #pragma unroll
        for (int n = 0; n < NPB; ++n) {
            if (half == 0) {
                hid[n][t] = (lds[(4 * n + 0) * 2048 + t] + lds[(4 * n + 1) * 2048 + t])
                          + (lds[(4 * n + 2) * 2048 + t] + lds[(4 * n + 3) * 2048 + t]);
            } else {
                const float num = (float)(s_cnt[4 * n] + s_cnt[4 * n + 1]
                                        + s_cnt[4 * n + 2] + s_cnt[4 * n + 3]);
                const float inv = 1.0f / fmaxf(num, 1.0f);
                hid[n][Ddim + t] =
                    ((lds[(4 * n + 0) * 2048 + 256 + t] + lds[(4 * n + 1) * 2048 + 256 + t])
                   + (lds[(4 * n + 2) * 2048 + 256 + t] + lds[(4 * n + 3) * 2048 + 256 + t])) * inv;
            }
        }
    }
    __syncthreads();

    // GEMM: thread -> (col t, node tid>>8). Both halves load the same W[k][t]
    // at the same time -> L1 dedup; W read once per block from L2.
    const int t = tid & (Ddim - 1);
    const int n = tid >> 8;
    float acc0 = bmap[t];
    float acc1 = 0.f;
    const float4* __restrict__ h = (const float4*)hid[n];

    #pragma unroll 4
    for (int k4 = 0; k4 < (2 * Ddim) / 4; ++k4) {
        const float4 ha = h[k4];            // ds_read_b128, wave-broadcast
        const int k = k4 * 4;
        const float w0 = Wmap[(size_t)(k + 0) * Hdim + t];
        const float w1 = Wmap[(size_t)(k + 1) * Hdim + t];
        const float w2 = Wmap[(size_t)(k + 2) * Hdim + t];
        const float w3 = Wmap[(size_t)(k + 3) * Hdim + t];
        acc0 = fmaf(ha.x, w0, acc0);
        acc1 = fmaf(ha.y, w1, acc1);
        acc0 = fmaf(ha.z, w2, acc0);
        acc1 = fmaf(ha.w, w3, acc1);
    }

    const float acc = acc0 + acc1;
    const float r = acc > 0.f ? acc : 0.01f * acc;
    out[(size_t)(blockIdx.x * NPB + n) * Hdim + t] = r;
}

extern "C" void kernel_launch(void* const* d_in, const int* in_sizes, int n_in,
                              void* d_out, int out_size, void* d_ws, size_t ws_size,
                              hipStream_t stream) {
    const float* src   = (const float*)d_in[0];
    const float* neigh = (const float*)d_in[1];
    const float* Wmap  = (const float*)d_in[2];
    const float* bmap  = (const float*)d_in[3];
    float* out = (float*)d_out;

    dim3 grid((Bdim * Sdim) / NPB);   // 1024 blocks, 2 nodes each
    dim3 block(NT);
    gcn_dma<<<grid, block, 0, stream>>>(src, neigh, Wmap, bmap, out);
}